// Round 5
// baseline (304.479 us; speedup 1.0000x reference)
//
#include <hip/hip_runtime.h>
#include <math.h>

// Problem constants: B=4, S=2048, D=1024, fp32 in/out
constexpr int B_ = 4;
constexpr int S_ = 2048;
constexpr int D_ = 1024;
constexpr long BS_ = (long)B_ * S_;     // 8192 rows
constexpr float EPS_ = 1e-5f;

typedef __attribute__((ext_vector_type(8))) short   bfx8;   // MFMA A/B frag
typedef __attribute__((ext_vector_type(4))) float   fx4;    // MFMA C/D frag
typedef __attribute__((ext_vector_type(8))) unsigned short u16x8;

__device__ __forceinline__ unsigned short f2bf(float f) {
    unsigned int x = __float_as_uint(f);
    x = (x + 0x7fffu + ((x >> 16) & 1u)) >> 16;   // RNE
    return (unsigned short)x;
}
__device__ __forceinline__ float bf2f(unsigned short u) {
    return __uint_as_float(((unsigned int)u) << 16);
}

// async global->LDS, 16B/lane. LDS base wave-uniform; HW adds lane*16B.
__device__ __forceinline__ void gload16(const void* g, void* l) {
    __builtin_amdgcn_global_load_lds(
        (const __attribute__((address_space(1))) unsigned int*)g,
        (__attribute__((address_space(3))) unsigned int*)l,
        16, 0, 0);
}

// =======================================================================
// bf16 MFMA GEMM with counted-vmcnt pipeline (T3-min + T4 + T2):
//   BM=256 x BN=128, BK=64, 512 thr (8 waves as 4Mx2N), per-wave 64x64
//   = 4x4 frags of 16x16, mfma_f32_16x16x32_bf16. LDS 96KB (dbuf).
// Per K-tile: STAGE(t+1); vmcnt(6); s_barrier; ds_read(swz); lgkmcnt(0);
//             MFMA x32; s_barrier.   vmcnt NEVER drains to 0 in-loop.
// T2 swizzle (both-sides involution, m104/m201): LDS dest linear,
//   global source k-slot ^= row&7, read k-slot ^= row&7  -> 2-way free.
// A: [M,K] bf16 row-major. Bt: [N,K] bf16 row-major (B transposed).
// MODE 0: QKV proj (z: 0=Q bf16, 1=K bf16, 2=V^T bf16 [b][D][S]), +bias.
// MODE 1: scores -> bf16, scaled by alpha.   MODE 2: PV -> fp32.
// =======================================================================
template<int MODE>
__global__ __launch_bounds__(512, 2)
void mgemm(const unsigned short* __restrict__ A,
           const unsigned short* __restrict__ Bt,
           void* __restrict__ C0, void* __restrict__ C1, void* __restrict__ C2,
           const float* __restrict__ bias,
           int K, int N, long bA, long bB, long bC, float alpha)
{
    const int z = blockIdx.z;
    A  += z * bA;
    Bt += z * bB;

    __shared__ __align__(16) unsigned short As[2][256 * 64];   // 32KB each
    __shared__ __align__(16) unsigned short Bs[2][128 * 64];   // 16KB each

    const int tid  = threadIdx.x;
    const int lane = tid & 63;
    const int w    = tid >> 6;                // wave 0..7
    const int wr   = w >> 1, wc = w & 1;      // 4Mx2N wave grid
    const int row0 = blockIdx.x * 256;
    const int col0 = blockIdx.y * 128;

    // ---- staging map (linear LDS dest, swizzled global source) ----
    // chunk c, wave w, lane l -> slot = c*512 + w*64 + l; row = slot>>3,
    // 16B-kslot s = l&7 fetches global kslot s ^ (row&7) = (l&7)^(l>>3).
    const int lrow = lane >> 3;                       // 0..7
    const int kswz = ((lane & 7) ^ lrow) * 8;         // elements
    const unsigned short* gA = A  + (long)(row0 + w * 8 + lrow) * K + kswz;
    const unsigned short* gB = Bt + (long)(col0 + w * 8 + lrow) * K + kswz;
    const long cA = (long)64 * K;                     // chunk row stride

    fx4 acc[4][4];
#pragma unroll
    for (int i = 0; i < 4; ++i)
#pragma unroll
        for (int j = 0; j < 4; ++j) acc[i][j] = fx4{0.f, 0.f, 0.f, 0.f};

    const int fr = lane & 15;            // frag row (A) / col (B,C)
    const int q  = lane >> 4;            // 0..3: which 16B k-slot of 32-sub
    const int sw = fr & 7;               // read-side swizzle key
    const int nt = K >> 6;               // K-tiles of 64

    // STAGE one K-tile into buffer b: A 4 chunks + B 2 chunks = 6 loads
    auto STAGE = [&](int b, int t) {
        const long ko = (long)t * 64;
#pragma unroll
        for (int c = 0; c < 4; ++c)
            gload16(gA + c * cA + ko, &As[b][c * 4096 + w * 512]);
#pragma unroll
        for (int c = 0; c < 2; ++c)
            gload16(gB + c * cA + ko, &Bs[b][c * 4096 + w * 512]);
    };

    STAGE(0, 0);                         // prologue (6 in flight)

    for (int t = 0; t < nt; ++t) {
        const int cur = t & 1;
        if (t + 1 < nt) {
            STAGE(cur ^ 1, t + 1);       // 12 in flight
            asm volatile("s_waitcnt vmcnt(6)" ::: "memory");   // tile t done
        } else {
            asm volatile("s_waitcnt vmcnt(0)" ::: "memory");   // last tile
        }
        __builtin_amdgcn_s_barrier();    // everyone's STAGE(t) complete
        __builtin_amdgcn_sched_barrier(0);

        bfx8 af[4][2], bf[4][2];
#pragma unroll
        for (int i = 0; i < 4; ++i) {
            const int mr = wr * 64 + i * 16 + fr;
#pragma unroll
            for (int ks = 0; ks < 2; ++ks)
                af[i][ks] = *(const bfx8*)&As[cur][mr * 64 + (((ks * 4 + q) ^ sw) * 8)];
        }
#pragma unroll
        for (int j = 0; j < 4; ++j) {
            const int nr = wc * 64 + j * 16 + fr;
#pragma unroll
            for (int ks = 0; ks < 2; ++ks)
                bf[j][ks] = *(const bfx8*)&Bs[cur][nr * 64 + (((ks * 4 + q) ^ sw) * 8)];
        }
        asm volatile("s_waitcnt lgkmcnt(0)" ::: "memory");
        __builtin_amdgcn_sched_barrier(0);   // rule #18: pin MFMA below wait

        __builtin_amdgcn_s_setprio(1);
#pragma unroll
        for (int ks = 0; ks < 2; ++ks)
#pragma unroll
            for (int i = 0; i < 4; ++i)
#pragma unroll
                for (int j = 0; j < 4; ++j)
                    acc[i][j] = __builtin_amdgcn_mfma_f32_16x16x32_bf16(
                        af[i][ks], bf[j][ks], acc[i][j], 0, 0, 0);
        __builtin_amdgcn_s_setprio(0);

        __builtin_amdgcn_s_barrier();    // all reads done -> buf[cur] reusable
        __builtin_amdgcn_sched_barrier(0);
    }

    // ---- epilogue. C/D frag: col = lane&15, row = (lane>>4)*4 + r  [m89]
    const int r0 = q * 4;
    if (MODE == 0) {
        const float* bz = bias + z * N;
        if (z < 2) {
            unsigned short* C = (unsigned short*)(z == 0 ? C0 : C1);
#pragma unroll
            for (int i = 0; i < 4; ++i) {
                const int rg0 = row0 + wr * 64 + i * 16 + r0;
#pragma unroll
                for (int j = 0; j < 4; ++j) {
                    const int cg = col0 + wc * 64 + j * 16 + fr;
                    const float bb = bz[cg];
#pragma unroll
                    for (int r = 0; r < 4; ++r)
                        C[(long)(rg0 + r) * N + cg] = f2bf(acc[i][j][r] + bb);
                }
            }
        } else {  // V: store transposed bf16 [b][D][S]
            unsigned short* Vt = (unsigned short*)C2;
#pragma unroll
            for (int i = 0; i < 4; ++i) {
                const int rg0 = row0 + wr * 64 + i * 16 + r0;
                const int b   = rg0 >> 11;          // /2048 (tiles never straddle)
                const int sv  = rg0 & 2047;
#pragma unroll
                for (int j = 0; j < 4; ++j) {
                    const int cg = col0 + wc * 64 + j * 16 + fr;
                    const float bb = bz[cg];
                    short4 pk;
                    pk.x = (short)f2bf(acc[i][j][0] + bb);
                    pk.y = (short)f2bf(acc[i][j][1] + bb);
                    pk.z = (short)f2bf(acc[i][j][2] + bb);
                    pk.w = (short)f2bf(acc[i][j][3] + bb);
                    *(short4*)&Vt[(long)b * D_ * S_ + (long)cg * S_ + sv] = pk;
                }
            }
        }
    } else if (MODE == 1) {
        unsigned short* C = (unsigned short*)C0 + z * bC;
#pragma unroll
        for (int i = 0; i < 4; ++i) {
            const int rg0 = row0 + wr * 64 + i * 16 + r0;
#pragma unroll
            for (int j = 0; j < 4; ++j) {
                const int cg = col0 + wc * 64 + j * 16 + fr;
#pragma unroll
                for (int r = 0; r < 4; ++r)
                    C[(long)(rg0 + r) * N + cg] = f2bf(acc[i][j][r] * alpha);
            }
        }
    } else {
        float* C = (float*)C0 + z * bC;
#pragma unroll
        for (int i = 0; i < 4; ++i) {
            const int rg0 = row0 + wr * 64 + i * 16 + r0;
#pragma unroll
            for (int j = 0; j < 4; ++j) {
                const int cg = col0 + wc * 64 + j * 16 + fr;
#pragma unroll
                for (int r = 0; r < 4; ++r)
                    C[(long)(rg0 + r) * N + cg] = acc[i][j][r];
            }
        }
    }
}

// ---------- fp32 -> bf16 cast, 8 elements/thread ----------
__global__ __launch_bounds__(256)
void cast_bf16(const float* __restrict__ in, unsigned short* __restrict__ out)
{
    const long i = (long)blockIdx.x * 256 + threadIdx.x;
    const float4 a = ((const float4*)in)[2 * i];
    const float4 b = ((const float4*)in)[2 * i + 1];
    u16x8 v;
    v[0] = f2bf(a.x); v[1] = f2bf(a.y); v[2] = f2bf(a.z); v[3] = f2bf(a.w);
    v[4] = f2bf(b.x); v[5] = f2bf(b.y); v[6] = f2bf(b.z); v[7] = f2bf(b.w);
    *(u16x8*)(out + i * 8) = v;
}

// ---------- W -> W^T bf16 (3 matrices via z) ----------
__global__ __launch_bounds__(256)
void wtrans_cast(const float* __restrict__ w0, const float* __restrict__ w1,
                 const float* __restrict__ w2, unsigned short* __restrict__ out)
{
    const float* W = blockIdx.z == 0 ? w0 : (blockIdx.z == 1 ? w1 : w2);
    unsigned short* O = out + (long)blockIdx.z * D_ * D_;
    __shared__ float t[32][33];
    const int tx = threadIdx.x & 31, ty = threadIdx.x >> 5;   // ty 0..7
    const int k0 = blockIdx.x * 32, n0 = blockIdx.y * 32;
#pragma unroll
    for (int r = 0; r < 4; ++r)
        t[ty + 8 * r][tx] = W[(long)(k0 + ty + 8 * r) * D_ + n0 + tx];
    __syncthreads();
#pragma unroll
    for (int r = 0; r < 4; ++r)
        O[(long)(n0 + ty + 8 * r) * D_ + k0 + tx] = f2bf(t[tx][ty + 8 * r]);
}

// ---------- row softmax over 2048 bf16, in place ----------
__global__ __launch_bounds__(256)
void softmax_bf16(unsigned short* __restrict__ P, long bStride)
{
    unsigned short* row = P + blockIdx.y * bStride + (long)blockIdx.x * S_;
    const int tid = threadIdx.x, lane = tid & 63, wid = tid >> 6;
    __shared__ float sm[4], ss[4];

    u16x8 v = *(u16x8*)(row + tid * 8);
    float f[8];
#pragma unroll
    for (int i = 0; i < 8; ++i) f[i] = bf2f(v[i]);

    float m = f[0];
#pragma unroll
    for (int i = 1; i < 8; ++i) m = fmaxf(m, f[i]);
#pragma unroll
    for (int o = 1; o < 64; o <<= 1) m = fmaxf(m, __shfl_xor(m, o));
    if (lane == 0) sm[wid] = m;
    __syncthreads();
    m = fmaxf(fmaxf(sm[0], sm[1]), fmaxf(sm[2], sm[3]));

    float s = 0.f;
#pragma unroll
    for (int i = 0; i < 8; ++i) { f[i] = __expf(f[i] - m); s += f[i]; }
#pragma unroll
    for (int o = 1; o < 64; o <<= 1) s += __shfl_xor(s, o);
    if (lane == 0) ss[wid] = s;
    __syncthreads();
    s = ss[0] + ss[1] + ss[2] + ss[3];

    const float inv = 1.0f / s;
#pragma unroll
    for (int i = 0; i < 8; ++i) v[i] = f2bf(f[i] * inv);
    *(u16x8*)(row + tid * 8) = v;
}

// ---------- h = x + attn; out = LN(h)*gamma + beta ----------
__global__ __launch_bounds__(256)
void resid_ln(const float* __restrict__ x, const float* __restrict__ attn,
              const float* __restrict__ gamma, const float* __restrict__ beta,
              float* __restrict__ out)
{
    const long row = blockIdx.x;
    const int tid = threadIdx.x, lane = tid & 63, wid = tid >> 6;
    __shared__ float s1[4], s2[4];

    float4 xv = ((const float4*)(x + row * D_))[tid];
    float4 av = ((const float4*)(attn + row * D_))[tid];
    float4 h;
    h.x = xv.x + av.x; h.y = xv.y + av.y; h.z = xv.z + av.z; h.w = xv.w + av.w;

    float sum = h.x + h.y + h.z + h.w;
#pragma unroll
    for (int o = 1; o < 64; o <<= 1) sum += __shfl_xor(sum, o);
    if (lane == 0) s1[wid] = sum;
    __syncthreads();
    const float mu = (s1[0] + s1[1] + s1[2] + s1[3]) * (1.0f / D_);

    float dx = h.x - mu, dy = h.y - mu, dz = h.z - mu, dw = h.w - mu;
    float sq = dx * dx + dy * dy + dz * dz + dw * dw;
#pragma unroll
    for (int o = 1; o < 64; o <<= 1) sq += __shfl_xor(sq, o);
    if (lane == 0) s2[wid] = sq;
    __syncthreads();
    const float var = (s2[0] + s2[1] + s2[2] + s2[3]) * (1.0f / D_);
    const float r = rsqrtf(var + EPS_);

    float4 g = ((const float4*)gamma)[tid];
    float4 b = ((const float4*)beta)[tid];
    float4 o4;
    o4.x = dx * r * g.x + b.x;
    o4.y = dy * r * g.y + b.y;
    o4.z = dz * r * g.z + b.z;
    o4.w = dw * r * g.w + b.w;
    ((float4*)(out + row * D_))[tid] = o4;
}

extern "C" void kernel_launch(void* const* d_in, const int* in_sizes, int n_in,
                              void* d_out, int out_size, void* d_ws, size_t ws_size,
                              hipStream_t stream) {
    (void)in_sizes; (void)n_in; (void)out_size;
    const float* x     = (const float*)d_in[0];
    const float* Wq    = (const float*)d_in[1];
    const float* bq    = (const float*)d_in[2];
    const float* Wk    = (const float*)d_in[3];
    const float* bk    = (const float*)d_in[4];
    const float* Wv    = (const float*)d_in[5];
    const float* bv    = (const float*)d_in[6];
    const float* gamma = (const float*)d_in[7];
    const float* beta  = (const float*)d_in[8];
    float* out = (float*)d_out;

    // ---- workspace layout (bytes) ----
    const size_t OFF_XB = 0;                                  // x bf16      16.78 MB
    const size_t OFF_WT = OFF_XB + (size_t)BS_ * D_ * 2;      // W^T bf16     6.29 MB
    const size_t OFF_BC = OFF_WT + (size_t)3 * D_ * D_ * 2;   // bias f32     12 KB
    const size_t OFF_QB = OFF_BC + (size_t)3 * D_ * 4;        // Q bf16      16.78 MB
    const size_t OFF_KB = OFF_QB + (size_t)BS_ * D_ * 2;      // K bf16      16.78 MB
    const size_t OFF_VT = OFF_KB + (size_t)BS_ * D_ * 2;      // V^T bf16    16.78 MB
    const size_t OFF_O  = OFF_VT + (size_t)BS_ * D_ * 2;      // attn f32    33.55 MB
    const size_t OFF_P  = OFF_O  + (size_t)BS_ * D_ * 4;      // scores bf16
    const size_t SZ_P1  = (size_t)S_ * S_ * 2;                //  8.39 MB / batch
    const bool full = ws_size >= OFF_P + 4 * SZ_P1;           // 140.5 MB total

    unsigned short* xb  = (unsigned short*)((char*)d_ws + OFF_XB);
    unsigned short* Wtb = (unsigned short*)((char*)d_ws + OFF_WT);
    float*          bc  = (float*)((char*)d_ws + OFF_BC);
    unsigned short* Qb  = (unsigned short*)((char*)d_ws + OFF_QB);
    unsigned short* Kb  = (unsigned short*)((char*)d_ws + OFF_KB);
    unsigned short* Vtb = (unsigned short*)((char*)d_ws + OFF_VT);
    float*          O   = (float*)((char*)d_ws + OFF_O);
    unsigned short* Pb  = (unsigned short*)((char*)d_ws + OFF_P);

    // bias concat (tiny d2d copies, graph-capture safe)
    hipMemcpyAsync(bc,          bq, (size_t)D_ * 4, hipMemcpyDeviceToDevice, stream);
    hipMemcpyAsync(bc + D_,     bk, (size_t)D_ * 4, hipMemcpyDeviceToDevice, stream);
    hipMemcpyAsync(bc + 2 * D_, bv, (size_t)D_ * 4, hipMemcpyDeviceToDevice, stream);

    // casts
    cast_bf16<<<dim3((int)(BS_ * D_ / 8 / 256)), 256, 0, stream>>>(x, xb);
    wtrans_cast<<<dim3(32, 32, 3), 256, 0, stream>>>(Wq, Wk, Wv, Wtb);

    // 1) QKV projection: [8192,1024] @ [1024,1024] -> Q,K bf16; V transposed
    mgemm<0><<<dim3(32, 8, 3), 512, 0, stream>>>(
        xb, Wtb, Qb, Kb, Vtb, bc, D_, D_,
        0L, (long)D_ * D_, 0L, 1.0f);

    // 2) attention, z-batched when workspace allows
    const int  chunk   = full ? 4 : 1;
    const long pstride = full ? (long)S_ * S_ : 0L;
    const long sd      = (long)S_ * D_;
    const long ds      = (long)D_ * S_;
    for (int b0 = 0; b0 < B_; b0 += chunk) {
        // scores = Q @ K^T / 32  -> bf16 [S,S]
        mgemm<1><<<dim3(8, 16, chunk), 512, 0, stream>>>(
            Qb + b0 * sd, Kb + b0 * sd, Pb, nullptr, nullptr, nullptr,
            D_, S_, sd, sd, pstride, 1.0f / 32.0f);
        // softmax rows in place (bf16)
        softmax_bf16<<<dim3(S_, chunk), 256, 0, stream>>>(Pb, pstride);
        // attn_out = P @ V -> fp32 (B^T = V transposed [D,S])
        mgemm<2><<<dim3(8, 8, chunk), 512, 0, stream>>>(
            Pb, Vtb + b0 * ds, O + b0 * sd, nullptr, nullptr, nullptr,
            S_, D_, pstride, ds, sd, 1.0f);
    }

    // 3) residual + LayerNorm (fp32)
    resid_ln<<<dim3((int)BS_), 256, 0, stream>>>(x, O, gamma, beta, out);
}

// Round 6
// 279.563 us; speedup vs baseline: 1.0891x; 1.0891x over previous
//
#include <hip/hip_runtime.h>
#include <math.h>

// Problem constants: B=4, S=2048, D=1024, fp32 in/out
constexpr int B_ = 4;
constexpr int S_ = 2048;
constexpr int D_ = 1024;
constexpr long BS_ = (long)B_ * S_;     // 8192 rows
constexpr float EPS_ = 1e-5f;

typedef __attribute__((ext_vector_type(8))) short   bfx8;   // MFMA A/B frag
typedef __attribute__((ext_vector_type(4))) float   fx4;    // MFMA C/D frag
typedef __attribute__((ext_vector_type(8))) unsigned short u16x8;

__device__ __forceinline__ unsigned short f2bf(float f) {
    unsigned int x = __float_as_uint(f);
    x = (x + 0x7fffu + ((x >> 16) & 1u)) >> 16;   // RNE
    return (unsigned short)x;
}
__device__ __forceinline__ float bf2f(unsigned short u) {
    return __uint_as_float(((unsigned int)u) << 16);
}

// async global->LDS, 16B/lane. LDS base wave-uniform; HW adds lane*16B.
__device__ __forceinline__ void gload16(const void* g, void* l) {
    __builtin_amdgcn_global_load_lds(
        (const __attribute__((address_space(1))) unsigned int*)g,
        (__attribute__((address_space(3))) unsigned int*)l,
        16, 0, 0);
}

// =======================================================================
// bf16 MFMA GEMM, 4-phase free-running schedule (T3+T4+T2+T5):
//   BM=256 x BN tile, BK=64, 512 thr (8 waves as 2Mx4N), per-wave
//   128 x BN/4 output. ONE vmcnt(0)+s_barrier per K-tile; phases inside
//   a tile have NO barrier -> waves desync into load/MFMA roles.
// Per K-tile t (buf ct complete): 4 quadrant phases, each
//   {ds_read quadrant frags ; issue stage chunks of t+1 (phases 0-2 only,
//    so the tile-end vmcnt(0) is covered by compute) ; lgkmcnt(0) ;
//    sched_barrier ; setprio(1) MFMA setprio(0)}.
// A/B frags reused across phases: 24 ds_read_b128/wave/tile (not 48).
// T2 swizzle (verified 0 conflicts R5): LDS dest linear, global source
//   kslot ^= row&7, read kslot ^= row&7.
// A: [M,K] bf16 row-major. Bt: [N,K] bf16 row-major (B transposed).
// MODE 0: QKV proj (z: 0=Q bf16, 1=K bf16, 2=V^T bf16 [b][D][S]), +bias.
// MODE 1: scores -> bf16, scaled by alpha.   MODE 2: PV -> fp32.
// =======================================================================
template<int MODE, int BN>
__global__ __launch_bounds__(512, 2)
void mgemm(const unsigned short* __restrict__ A,
           const unsigned short* __restrict__ Bt,
           void* __restrict__ C0, void* __restrict__ C1, void* __restrict__ C2,
           const float* __restrict__ bias,
           int K, int N, long bA, long bB, long bC, float alpha)
{
    constexpr int BM = 256;
    constexpr int CH = 4 + BN / 64;      // stage chunks per K-tile (8 or 6)
    constexpr int WN = BN / 4;           // wave N-width (64 or 32)
    constexpr int NJ = BN / 128;         // frags per qb-half (2 or 1)
    constexpr int NF = 2 * NJ;           // N-frags per wave

    const int z = blockIdx.z;
    A  += z * bA;
    Bt += z * bB;

    __shared__ __align__(16) unsigned short As[2][BM * 64];  // 32KB each
    __shared__ __align__(16) unsigned short Bs[2][BN * 64];  // 32/16KB each

    const int tid  = threadIdx.x;
    const int lane = tid & 63;
    const int w    = tid >> 6;                // wave 0..7
    const int wr   = w >> 2, wc = w & 3;      // 2M x 4N wave grid
    const int row0 = blockIdx.x * BM;
    const int col0 = blockIdx.y * BN;

    // staging: chunk c = 64 rows; wave w stages rows c*64 + w*8 + (lane>>3),
    // source kslot = (lane&7) ^ (lane>>3)  (inverse swizzle), LDS dest linear.
    const int lrow = lane >> 3;
    const int kswz = ((lane & 7) ^ lrow) * 8;
    const unsigned short* gA = A  + (long)(row0 + w * 8 + lrow) * K + kswz;
    const unsigned short* gB = Bt + (long)(col0 + w * 8 + lrow) * K + kswz;
    const long cstr = (long)64 * K;

    auto stage = [&](int nb, int tt, int c) {
        if (c < 4) gload16(gA + c * cstr + (long)tt * 64,
                           &As[nb][c * 4096 + w * 512]);
        else       gload16(gB + (c - 4) * cstr + (long)tt * 64,
                           &Bs[nb][(c - 4) * 4096 + w * 512]);
    };

    const int fr = lane & 15;            // frag row (A) / col (B,C)
    const int q  = lane >> 4;            // frag k-slot quarter
    // swizzled read: logical kslot (ks*4+q) lives at physical ^(row&7)
    auto rd = [&](const unsigned short* buf, int r, int ks) {
        return *(const bfx8*)&buf[r * 64 + (((ks * 4 + q) ^ (r & 7)) << 3)];
    };

    fx4 acc[8][NF];
#pragma unroll
    for (int i = 0; i < 8; ++i)
#pragma unroll
        for (int j = 0; j < NF; ++j) acc[i][j] = fx4{0.f, 0.f, 0.f, 0.f};

    const int nt = K >> 6;               // K-tiles of 64

    // ---- prologue: stage tile 0 fully, drain, fence
#pragma unroll
    for (int c = 0; c < CH; ++c) stage(0, 0, c);
    asm volatile("s_waitcnt vmcnt(0)" ::: "memory");
    __builtin_amdgcn_s_barrier();
    asm volatile("" ::: "memory");
    __builtin_amdgcn_sched_barrier(0);

    bfx8 af[4][2], bf0[NJ][2], bf1[NJ][2];

    for (int t = 0; t < nt; ++t) {
        const int cur = t & 1, nb = cur ^ 1, tn = t + 1;
        const bool pf = tn < nt;
        const unsigned short* Ab = As[cur];
        const unsigned short* Bb = Bs[cur];

        // ---- phase 0: A(qa=0) + B(qb=0); stage chunks 0..2
#pragma unroll
        for (int i = 0; i < 4; ++i) {
            af[i][0] = rd(Ab, wr * 128 + i * 16 + fr, 0);
            af[i][1] = rd(Ab, wr * 128 + i * 16 + fr, 1);
        }
#pragma unroll
        for (int j = 0; j < NJ; ++j) {
            bf0[j][0] = rd(Bb, wc * WN + j * 16 + fr, 0);
            bf0[j][1] = rd(Bb, wc * WN + j * 16 + fr, 1);
        }
        if (pf) { stage(nb, tn, 0); stage(nb, tn, 1); stage(nb, tn, 2); }
        asm volatile("s_waitcnt lgkmcnt(0)" ::: "memory");
        __builtin_amdgcn_sched_barrier(0);
        __builtin_amdgcn_s_setprio(1);
#pragma unroll
        for (int ks = 0; ks < 2; ++ks)
#pragma unroll
            for (int i = 0; i < 4; ++i)
#pragma unroll
                for (int j = 0; j < NJ; ++j)
                    acc[i][j] = __builtin_amdgcn_mfma_f32_16x16x32_bf16(
                        af[i][ks], bf0[j][ks], acc[i][j], 0, 0, 0);
        __builtin_amdgcn_s_setprio(0);

        // ---- phase 1: B(qb=1); stage chunks 3..5
#pragma unroll
        for (int j = 0; j < NJ; ++j) {
            bf1[j][0] = rd(Bb, wc * WN + (NJ + j) * 16 + fr, 0);
            bf1[j][1] = rd(Bb, wc * WN + (NJ + j) * 16 + fr, 1);
        }
        if (pf) { stage(nb, tn, 3); stage(nb, tn, 4); stage(nb, tn, 5); }
        asm volatile("s_waitcnt lgkmcnt(0)" ::: "memory");
        __builtin_amdgcn_sched_barrier(0);
        __builtin_amdgcn_s_setprio(1);
#pragma unroll
        for (int ks = 0; ks < 2; ++ks)
#pragma unroll
            for (int i = 0; i < 4; ++i)
#pragma unroll
                for (int j = 0; j < NJ; ++j)
                    acc[i][NJ + j] = __builtin_amdgcn_mfma_f32_16x16x32_bf16(
                        af[i][ks], bf1[j][ks], acc[i][NJ + j], 0, 0, 0);
        __builtin_amdgcn_s_setprio(0);

        // ---- phase 2: A(qa=1); stage chunks 6..7 (BN=256 only)
#pragma unroll
        for (int i = 0; i < 4; ++i) {
            af[i][0] = rd(Ab, wr * 128 + 64 + i * 16 + fr, 0);
            af[i][1] = rd(Ab, wr * 128 + 64 + i * 16 + fr, 1);
        }
        if constexpr (CH == 8) {
            if (pf) { stage(nb, tn, 6); stage(nb, tn, 7); }
        }
        asm volatile("s_waitcnt lgkmcnt(0)" ::: "memory");
        __builtin_amdgcn_sched_barrier(0);
        __builtin_amdgcn_s_setprio(1);
#pragma unroll
        for (int ks = 0; ks < 2; ++ks)
#pragma unroll
            for (int i = 0; i < 4; ++i)
#pragma unroll
                for (int j = 0; j < NJ; ++j)
                    acc[4 + i][j] = __builtin_amdgcn_mfma_f32_16x16x32_bf16(
                        af[i][ks], bf0[j][ks], acc[4 + i][j], 0, 0, 0);
        __builtin_amdgcn_s_setprio(0);

        // ---- phase 3: no reads (af=qa1, bf1 already live)
        __builtin_amdgcn_s_setprio(1);
#pragma unroll
        for (int ks = 0; ks < 2; ++ks)
#pragma unroll
            for (int i = 0; i < 4; ++i)
#pragma unroll
                for (int j = 0; j < NJ; ++j)
                    acc[4 + i][NJ + j] = __builtin_amdgcn_mfma_f32_16x16x32_bf16(
                        af[i][ks], bf1[j][ks], acc[4 + i][NJ + j], 0, 0, 0);
        __builtin_amdgcn_s_setprio(0);

        // ---- tile boundary: drain own stages, one barrier
        asm volatile("s_waitcnt vmcnt(0)" ::: "memory");
        __builtin_amdgcn_s_barrier();
        asm volatile("" ::: "memory");
        __builtin_amdgcn_sched_barrier(0);
    }

    // ---- epilogue. C/D frag: col = lane&15, row = (lane>>4)*4 + r  [m89]
    const int r0v = q * 4;
    if (MODE == 0) {
        const float* bz = bias + z * N;
        if (z < 2) {
            unsigned short* C = (unsigned short*)(z == 0 ? C0 : C1);
#pragma unroll
            for (int ai = 0; ai < 8; ++ai) {
                const int rg0 = row0 + wr * 128 + ai * 16 + r0v;
#pragma unroll
                for (int bj = 0; bj < NF; ++bj) {
                    const int cg = col0 + wc * WN + bj * 16 + fr;
                    const float bb = bz[cg];
#pragma unroll
                    for (int r = 0; r < 4; ++r)
                        C[(long)(rg0 + r) * N + cg] = f2bf(acc[ai][bj][r] + bb);
                }
            }
        } else {  // V: store transposed bf16 [b][D][S]
            unsigned short* Vt = (unsigned short*)C2;
#pragma unroll
            for (int ai = 0; ai < 8; ++ai) {
                const int rg0 = row0 + wr * 128 + ai * 16 + r0v;
                const int b   = rg0 >> 11;          // /2048 (never straddles)
                const int sv  = rg0 & 2047;
#pragma unroll
                for (int bj = 0; bj < NF; ++bj) {
                    const int cg = col0 + wc * WN + bj * 16 + fr;
                    const float bb = bz[cg];
                    short4 pk;
                    pk.x = (short)f2bf(acc[ai][bj][0] + bb);
                    pk.y = (short)f2bf(acc[ai][bj][1] + bb);
                    pk.z = (short)f2bf(acc[ai][bj][2] + bb);
                    pk.w = (short)f2bf(acc[ai][bj][3] + bb);
                    *(short4*)&Vt[(long)b * D_ * S_ + (long)cg * S_ + sv] = pk;
                }
            }
        }
    } else if (MODE == 1) {
        unsigned short* C = (unsigned short*)C0 + z * bC;
#pragma unroll
        for (int ai = 0; ai < 8; ++ai) {
            const int rg0 = row0 + wr * 128 + ai * 16 + r0v;
#pragma unroll
            for (int bj = 0; bj < NF; ++bj) {
                const int cg = col0 + wc * WN + bj * 16 + fr;
#pragma unroll
                for (int r = 0; r < 4; ++r)
                    C[(long)(rg0 + r) * N + cg] = f2bf(acc[ai][bj][r] * alpha);
            }
        }
    } else {
        float* C = (float*)C0 + z * bC;
#pragma unroll
        for (int ai = 0; ai < 8; ++ai) {
            const int rg0 = row0 + wr * 128 + ai * 16 + r0v;
#pragma unroll
            for (int bj = 0; bj < NF; ++bj) {
                const int cg = col0 + wc * WN + bj * 16 + fr;
#pragma unroll
                for (int r = 0; r < 4; ++r)
                    C[(long)(rg0 + r) * N + cg] = acc[ai][bj][r];
            }
        }
    }
}

// ---------- fp32 -> bf16 cast, 8 elements/thread ----------
__global__ __launch_bounds__(256)
void cast_bf16(const float* __restrict__ in, unsigned short* __restrict__ out)
{
    const long i = (long)blockIdx.x * 256 + threadIdx.x;
    const float4 a = ((const float4*)in)[2 * i];
    const float4 b = ((const float4*)in)[2 * i + 1];
    u16x8 v;
    v[0] = f2bf(a.x); v[1] = f2bf(a.y); v[2] = f2bf(a.z); v[3] = f2bf(a.w);
    v[4] = f2bf(b.x); v[5] = f2bf(b.y); v[6] = f2bf(b.z); v[7] = f2bf(b.w);
    *(u16x8*)(out + i * 8) = v;
}

// ---------- W -> W^T bf16 (3 matrices via z) ----------
__global__ __launch_bounds__(256)
void wtrans_cast(const float* __restrict__ w0, const float* __restrict__ w1,
                 const float* __restrict__ w2, unsigned short* __restrict__ out)
{
    const float* W = blockIdx.z == 0 ? w0 : (blockIdx.z == 1 ? w1 : w2);
    unsigned short* O = out + (long)blockIdx.z * D_ * D_;
    __shared__ float t[32][33];
    const int tx = threadIdx.x & 31, ty = threadIdx.x >> 5;   // ty 0..7
    const int k0 = blockIdx.x * 32, n0 = blockIdx.y * 32;
#pragma unroll
    for (int r = 0; r < 4; ++r)
        t[ty + 8 * r][tx] = W[(long)(k0 + ty + 8 * r) * D_ + n0 + tx];
    __syncthreads();
#pragma unroll
    for (int r = 0; r < 4; ++r)
        O[(long)(n0 + ty + 8 * r) * D_ + k0 + tx] = f2bf(t[tx][ty + 8 * r]);
}

// ---------- row softmax over 2048 bf16, in place ----------
__global__ __launch_bounds__(256)
void softmax_bf16(unsigned short* __restrict__ P, long bStride)
{
    unsigned short* row = P + blockIdx.y * bStride + (long)blockIdx.x * S_;
    const int tid = threadIdx.x, lane = tid & 63, wid = tid >> 6;
    __shared__ float sm[4], ss[4];

    u16x8 v = *(u16x8*)(row + tid * 8);
    float f[8];
#pragma unroll
    for (int i = 0; i < 8; ++i) f[i] = bf2f(v[i]);

    float m = f[0];
#pragma unroll
    for (int i = 1; i < 8; ++i) m = fmaxf(m, f[i]);
#pragma unroll
    for (int o = 1; o < 64; o <<= 1) m = fmaxf(m, __shfl_xor(m, o));
    if (lane == 0) sm[wid] = m;
    __syncthreads();
    m = fmaxf(fmaxf(sm[0], sm[1]), fmaxf(sm[2], sm[3]));

    float s = 0.f;
#pragma unroll
    for (int i = 0; i < 8; ++i) { f[i] = __expf(f[i] - m); s += f[i]; }
#pragma unroll
    for (int o = 1; o < 64; o <<= 1) s += __shfl_xor(s, o);
    if (lane == 0) ss[wid] = s;
    __syncthreads();
    s = ss[0] + ss[1] + ss[2] + ss[3];

    const float inv = 1.0f / s;
#pragma unroll
    for (int i = 0; i < 8; ++i) v[i] = f2bf(f[i] * inv);
    *(u16x8*)(row + tid * 8) = v;
}

// ---------- h = x + attn; out = LN(h)*gamma + beta ----------
__global__ __launch_bounds__(256)
void resid_ln(const float* __restrict__ x, const float* __restrict__ attn,
              const float* __restrict__ gamma, const float* __restrict__ beta,
              float* __restrict__ out)
{
    const long row = blockIdx.x;
    const int tid = threadIdx.x, lane = tid & 63, wid = tid >> 6;
    __shared__ float s1[4], s2[4];

    float4 xv = ((const float4*)(x + row * D_))[tid];
    float4 av = ((const float4*)(attn + row * D_))[tid];
    float4 h;
    h.x = xv.x + av.x; h.y = xv.y + av.y; h.z = xv.z + av.z; h.w = xv.w + av.w;

    float sum = h.x + h.y + h.z + h.w;
#pragma unroll
    for (int o = 1; o < 64; o <<= 1) sum += __shfl_xor(sum, o);
    if (lane == 0) s1[wid] = sum;
    __syncthreads();
    const float mu = (s1[0] + s1[1] + s1[2] + s1[3]) * (1.0f / D_);

    float dx = h.x - mu, dy = h.y - mu, dz = h.z - mu, dw = h.w - mu;
    float sq = dx * dx + dy * dy + dz * dz + dw * dw;
#pragma unroll
    for (int o = 1; o < 64; o <<= 1) sq += __shfl_xor(sq, o);
    if (lane == 0) s2[wid] = sq;
    __syncthreads();
    const float var = (s2[0] + s2[1] + s2[2] + s2[3]) * (1.0f / D_);
    const float r = rsqrtf(var + EPS_);

    float4 g = ((const float4*)gamma)[tid];
    float4 b = ((const float4*)beta)[tid];
    float4 o4;
    o4.x = dx * r * g.x + b.x;
    o4.y = dy * r * g.y + b.y;
    o4.z = dz * r * g.z + b.z;
    o4.w = dw * r * g.w + b.w;
    ((float4*)(out + row * D_))[tid] = o4;
}

extern "C" void kernel_launch(void* const* d_in, const int* in_sizes, int n_in,
                              void* d_out, int out_size, void* d_ws, size_t ws_size,
                              hipStream_t stream) {
    (void)in_sizes; (void)n_in; (void)out_size;
    const float* x     = (const float*)d_in[0];
    const float* Wq    = (const float*)d_in[1];
    const float* bq    = (const float*)d_in[2];
    const float* Wk    = (const float*)d_in[3];
    const float* bk    = (const float*)d_in[4];
    const float* Wv    = (const float*)d_in[5];
    const float* bv    = (const float*)d_in[6];
    const float* gamma = (const float*)d_in[7];
    const float* beta  = (const float*)d_in[8];
    float* out = (float*)d_out;

    // ---- workspace layout (bytes) ----
    const size_t OFF_XB = 0;                                  // x bf16      16.78 MB
    const size_t OFF_WT = OFF_XB + (size_t)BS_ * D_ * 2;      // W^T bf16     6.29 MB
    const size_t OFF_BC = OFF_WT + (size_t)3 * D_ * D_ * 2;   // bias f32     12 KB
    const size_t OFF_QB = OFF_BC + (size_t)3 * D_ * 4;        // Q bf16      16.78 MB
    const size_t OFF_KB = OFF_QB + (size_t)BS_ * D_ * 2;      // K bf16      16.78 MB
    const size_t OFF_VT = OFF_KB + (size_t)BS_ * D_ * 2;      // V^T bf16    16.78 MB
    const size_t OFF_O  = OFF_VT + (size_t)BS_ * D_ * 2;      // attn f32    33.55 MB
    const size_t OFF_P  = OFF_O  + (size_t)BS_ * D_ * 4;      // scores bf16
    const size_t SZ_P1  = (size_t)S_ * S_ * 2;                //  8.39 MB / batch
    const bool full = ws_size >= OFF_P + 4 * SZ_P1;           // 140.5 MB total

    unsigned short* xb  = (unsigned short*)((char*)d_ws + OFF_XB);
    unsigned short* Wtb = (unsigned short*)((char*)d_ws + OFF_WT);
    float*          bc  = (float*)((char*)d_ws + OFF_BC);
    unsigned short* Qb  = (unsigned short*)((char*)d_ws + OFF_QB);
    unsigned short* Kb  = (unsigned short*)((char*)d_ws + OFF_KB);
    unsigned short* Vtb = (unsigned short*)((char*)d_ws + OFF_VT);
    float*          O   = (float*)((char*)d_ws + OFF_O);
    unsigned short* Pb  = (unsigned short*)((char*)d_ws + OFF_P);

    // bias concat (tiny d2d copies, graph-capture safe)
    hipMemcpyAsync(bc,          bq, (size_t)D_ * 4, hipMemcpyDeviceToDevice, stream);
    hipMemcpyAsync(bc + D_,     bk, (size_t)D_ * 4, hipMemcpyDeviceToDevice, stream);
    hipMemcpyAsync(bc + 2 * D_, bv, (size_t)D_ * 4, hipMemcpyDeviceToDevice, stream);

    // casts
    cast_bf16<<<dim3((int)(BS_ * D_ / 8 / 256)), 256, 0, stream>>>(x, xb);
    wtrans_cast<<<dim3(32, 32, 3), 256, 0, stream>>>(Wq, Wk, Wv, Wtb);

    // 1) QKV projection: [8192,1024] @ [1024,1024] -> Q,K bf16; V transposed
    mgemm<0, 128><<<dim3(32, 8, 3), 512, 0, stream>>>(
        xb, Wtb, Qb, Kb, Vtb, bc, D_, D_,
        0L, (long)D_ * D_, 0L, 1.0f);

    // 2) attention, z-batched when workspace allows
    const int  chunk   = full ? 4 : 1;
    const long pstride = full ? (long)S_ * S_ : 0L;
    const long sd      = (long)S_ * D_;
    const long ds      = (long)D_ * S_;
    for (int b0 = 0; b0 < B_; b0 += chunk) {
        // scores = Q @ K^T / 32  -> bf16 [S,S]   (256x256 tile, 256 blocks)
        mgemm<1, 256><<<dim3(8, 8, chunk), 512, 0, stream>>>(
            Qb + b0 * sd, Kb + b0 * sd, Pb, nullptr, nullptr, nullptr,
            D_, S_, sd, sd, pstride, 1.0f / 32.0f);
        // softmax rows in place (bf16)
        softmax_bf16<<<dim3(S_, chunk), 256, 0, stream>>>(Pb, pstride);
        // attn_out = P @ V -> fp32 (B^T = V transposed [D,S]; 256 blocks)
        mgemm<2, 128><<<dim3(8, 8, chunk), 512, 0, stream>>>(
            Pb, Vtb + b0 * ds, O + b0 * sd, nullptr, nullptr, nullptr,
            S_, D_, pstride, ds, sd, 1.0f);
    }

    // 3) residual + LayerNorm (fp32)
    resid_ln<<<dim3((int)BS_), 256, 0, stream>>>(x, O, gamma, beta, out);
}